// Round 1
// 480.652 us; speedup vs baseline: 1.2688x; 1.2688x over previous
//
#include <hip/hip_runtime.h>
#include <hip/hip_bf16.h>

#define NN 4096     // layer size n
#define RR 4        // displacement rank
#define BB 8192     // batch
#define CHUNK 64            // t-chunk for prefix kernels
#define NCHUNK (NN / CHUNK) // 64

typedef __bf16 bf16x8 __attribute__((ext_vector_type(8)));
typedef float f32x4 __attribute__((ext_vector_type(4)));
typedef unsigned short u16;
typedef unsigned int u32;

#define GLOBAL_AS(p) ((const __attribute__((address_space(1))) u32*)(p))
#define LDS_AS(p) ((__attribute__((address_space(3))) u32*)(p))

__device__ inline u32 pack_bf2(float lo, float hi) {
    __hip_bfloat162 h2 = __float22bfloat162_rn(make_float2(lo, hi));
    return *(u32*)&h2;
}

// ---------------------------------------------------------------------------
// Kernel 0: cast x (f32 row-major) -> bf16 row-major. Pure streaming.
// ---------------------------------------------------------------------------
__global__ __launch_bounds__(256) void cast_x_kernel(const float* __restrict__ x,
                                                     u16* __restrict__ xbf) {
    size_t i = (size_t)blockIdx.x * 256 + threadIdx.x;  // one 8-elem chunk each
    const float4* x4 = (const float4*)x;
    float4 a = x4[i * 2], b = x4[i * 2 + 1];
    uint4 o = make_uint4(pack_bf2(a.x, a.y), pack_bf2(a.z, a.w),
                         pack_bf2(b.x, b.y), pack_bf2(b.z, b.w));
    *(uint4*)(xbf + i * 8) = o;
}

// ---------------------------------------------------------------------------
// Kernel 1: block sums S_T(J,d) = sum_{t in chunk J} q(d,t)   (unchanged)
// ---------------------------------------------------------------------------
__global__ void ksum_kernel(const float* __restrict__ G, const float* __restrict__ H,
                            float* __restrict__ S_T) {
    int dblk = blockIdx.x & 15;
    int J = blockIdx.x >> 4;
    int d = dblk * 256 + threadIdx.x;
    int t0 = J * CHUNK;
    float acc = 0.f;
#pragma unroll 4
    for (int tt = 0; tt < CHUNK; ++tt) {
        int t = t0 + tt;
        float h0 = H[t], h1 = H[NN + t], h2 = H[2 * NN + t], h3 = H[3 * NN + t];
        int idx = (d + t) & (NN - 1);
        acc += G[idx] * h0 + G[NN + idx] * h1 + G[2 * NN + idx] * h2 + G[3 * NN + idx] * h3;
    }
    S_T[J * NN + d] = acc;
}

// ---------------------------------------------------------------------------
// Kernel 2: prefix + W write (bf16 ROW-MAJOR now) via LDS tile transpose.
// ---------------------------------------------------------------------------
__global__ __launch_bounds__(128) void kprefix_kernel(const float* __restrict__ G,
                                                      const float* __restrict__ H,
                                                      const float* __restrict__ S_T,
                                                      u16* __restrict__ W) {
    __shared__ u32 tile32[64 * 33];          // row stride 33 u32 = 66 u16
    u16* tile = (u16*)tile32;

    int itile = blockIdx.x >> 6;             // 64 row-tiles
    int J = blockIdx.x & 63;                 // 64 col-chunks
    int i0 = itile * 64, t0 = J * CHUNK;
    int dl = threadIdx.x;                    // 0..127
    int d = (i0 - t0 - 63 + dl) & (NN - 1);

    float pre = 0.f, tot = 0.f;
    for (int Jp = 0; Jp < NCHUNK; ++Jp) {
        float v = S_T[Jp * NN + d];
        if (Jp < J) pre += v;
        tot += v;
    }
    float acc = pre - 0.5f * tot;

#pragma unroll 4
    for (int tt = 0; tt < CHUNK; ++tt) {
        int t = t0 + tt;
        float h0 = H[t], h1 = H[NN + t], h2 = H[2 * NN + t], h3 = H[3 * NN + t];
        int idx = (d + t) & (NN - 1);
        acc += G[idx] * h0 + G[NN + idx] * h1 + G[2 * NN + idx] * h2 + G[3 * NN + idx] * h3;
        int r = dl + tt - 63;                // in-tile row
        if ((unsigned)r < 64u) {
            __hip_bfloat16 w = __float2bfloat16(acc);
            tile[r * 66 + tt] = *(u16*)&w;
        }
    }
    __syncthreads();

    // flush row-major: 16 rows/pass, 8 x 16B per row
    int r = threadIdx.x >> 3;                // 0..15
    int c8 = threadIdx.x & 7;
#pragma unroll
    for (int pass = 0; pass < 4; ++pass) {
        int rr = pass * 16 + r;
        const u32* s = &tile32[rr * 33 + c8 * 4];
        uint4 v = make_uint4(s[0], s[1], s[2], s[3]);
        *(uint4*)(W + (size_t)(i0 + rr) * NN + t0 + c8 * 8) = v;
    }
}

// ---------------------------------------------------------------------------
// Kernel 3: NT GEMM  y[b,i] = sum_j xbf[b,j] * W[i,j]  (f32 out)
// 256x256 tile, BK=64, 8 waves (2M x 4N), 8-phase counted-vmcnt schedule
// (T1 XCD swizzle + T2 LDS XOR swizzle + T3/T4 8-phase + T5 setprio).
//
// LDS: As/Bs [parity][half(128 rows)][chunk(64 rows)][64 rows][64 cols] bf16,
// 128 KiB total. Swizzle within a half: phys = lin ^ ((row&7)<<4).
// global_load_lds writes LDS linearly; the per-lane GLOBAL source address is
// pre-swizzled (rule: linear dest + inverse-swz source + swz on read).
//
// Stage events (2 loads/thread each): E1=B-lo, E2=B-hi, E3=A-chunk0(both
// halves), E4=A-chunk1(both halves). Phase schedule per iteration i
// (computes K-tiles 2i,2i+1; phases q0..q7, mi-pairs 01/23/45/67):
//   q0: E4(2i+1)  q1: E1(2i+2)  q2: E2(2i+2)  q3: E3(2i+2) +vmcnt(6)
//   q4: E4(2i+2)  q5: E1(2i+3)  q6: E2(2i+3)  q7: E3(2i+3) +vmcnt(6)
// Slot-lifetime check: every stage targets a slot last ds_read >=1 phase
// earlier (B read only at q0/q4; A chunk0 read q0-q1/q4-q5, chunk1 q2-q3/
// q6-q7). vmcnt(6) leaves exactly the 3 newest events (6 loads) in flight.
// ---------------------------------------------------------------------------

#define ST_A(kt, c) do { \
    const u16* s_ = srcA + (size_t)(c) * (64 * NN) + (size_t)(kt) * 64; \
    char* d_ = (char*)As + (((kt) & 1) * 32768) + ((c) * 8192) + t16; \
    __builtin_amdgcn_global_load_lds(GLOBAL_AS(s_), LDS_AS(d_), 16, 0, 0); \
    __builtin_amdgcn_global_load_lds(GLOBAL_AS(s_ + (size_t)128 * NN), LDS_AS(d_ + 16384), 16, 0, 0); \
} while (0)

#define ST_B(kt, hb) do { \
    const u16* s_ = srcB + (size_t)(hb) * (128 * NN) + (size_t)(kt) * 64; \
    char* d_ = (char*)Bs + (((kt) & 1) * 32768) + ((hb) * 16384) + t16; \
    __builtin_amdgcn_global_load_lds(GLOBAL_AS(s_), LDS_AS(d_), 16, 0, 0); \
    __builtin_amdgcn_global_load_lds(GLOBAL_AS(s_ + (size_t)64 * NN), LDS_AS(d_ + 8192), 16, 0, 0); \
} while (0)

#define AFR(cp, mi, ks) (*(const bf16x8*)(Abase + (cp) * 32768 + (mi) * 2048 + (sx ^ ((ks) << 6))))
#define BFR(cp, ni, ks) (*(const bf16x8*)(Bbase + (cp) * 32768 + (ni) * 2048 + (sx ^ ((ks) << 6))))

#define MM2(mi, ni, A0, A1) do { \
    acc[mi][ni] = __builtin_amdgcn_mfma_f32_16x16x32_bf16(A0, bq[2 * (ni)], acc[mi][ni], 0, 0, 0); \
    acc[mi][ni] = __builtin_amdgcn_mfma_f32_16x16x32_bf16(A1, bq[2 * (ni) + 1], acc[mi][ni], 0, 0, 0); \
} while (0)

#define PH(cp, mp, STAGES, WAITC) do { \
    bf16x8 xa0 = AFR(cp, mp, 0), xa1 = AFR(cp, mp, 1); \
    bf16x8 xa2 = AFR(cp, (mp) + 1, 0), xa3 = AFR(cp, (mp) + 1, 1); \
    if ((mp) == 0) { \
        bq[0] = BFR(cp, 0, 0); bq[1] = BFR(cp, 0, 1); \
        bq[2] = BFR(cp, 1, 0); bq[3] = BFR(cp, 1, 1); \
        bq[4] = BFR(cp, 2, 0); bq[5] = BFR(cp, 2, 1); \
        bq[6] = BFR(cp, 3, 0); bq[7] = BFR(cp, 3, 1); \
    } \
    STAGES; \
    WAITC; \
    __builtin_amdgcn_s_barrier(); \
    asm volatile("s_waitcnt lgkmcnt(0)" ::: "memory"); \
    __builtin_amdgcn_sched_barrier(0); \
    __builtin_amdgcn_s_setprio(1); \
    MM2(mp, 0, xa0, xa1); MM2(mp, 1, xa0, xa1); \
    MM2(mp, 2, xa0, xa1); MM2(mp, 3, xa0, xa1); \
    MM2((mp) + 1, 0, xa2, xa3); MM2((mp) + 1, 1, xa2, xa3); \
    MM2((mp) + 1, 2, xa2, xa3); MM2((mp) + 1, 3, xa2, xa3); \
    __builtin_amdgcn_s_setprio(0); \
    __builtin_amdgcn_s_barrier(); \
} while (0)

__global__ __launch_bounds__(512, 2) void gemm256_kernel(const u16* __restrict__ At,
                                                         const u16* __restrict__ Bt,
                                                         float* __restrict__ C) {
    __shared__ __align__(16) u16 As[2][2][2][64][64];  // 64 KiB
    __shared__ __align__(16) u16 Bs[2][2][2][64][64];  // 64 KiB

    // T1: XCD-aware swizzle; nwg = 512, 512 % 8 == 0 -> simple bijection
    int bid = blockIdx.x;
    int swz = (bid & 7) * 64 + (bid >> 3);
    int bx = swz & 15, by = swz >> 4;       // each XCD: 4 M-panels x all 16 N
    int m0 = by * 256, n0 = bx * 256;

    int t = threadIdx.x;
    int lane = t & 63, wave = t >> 6;
    int wm = wave >> 2, wn = wave & 3;      // 2M x 4N waves; per-wave C: 128x64
    int lrow = lane & 15, lq = lane >> 4;

    // staging: thread t covers linear LDS bytes [t*16); source col pre-swizzled
    int rowt = t >> 3;                                  // 0..63
    int colel = ((t & 7) ^ (rowt & 7)) << 3;            // element offset
    const u16* srcA = At + (size_t)(m0 + rowt) * NN + colel;
    const u16* srcB = Bt + (size_t)(n0 + rowt) * NN + colel;
    int t16 = t * 16;

    // ds_read bases (swizzled): frag byte = row*128 + ((lq<<4 | ks<<6) ^ ((row&7)<<4))
    const char* Abase = (const char*)As + wm * 16384 + lrow * 128;
    const char* Bbase = (const char*)Bs + (wn >> 1) * 16384 + (wn & 1) * 8192 + lrow * 128;
    int sx = (lq << 4) ^ ((lrow & 7) << 4);

    f32x4 acc[8][4] = {};
    bf16x8 bq[8];

    // prologue: K-tile 0 fully, K-tile 1 all but A-chunk1; keep 3 events in flight
    ST_B(0, 0); ST_B(0, 1); ST_A(0, 0); ST_A(0, 1);
    ST_B(1, 0); ST_B(1, 1); ST_A(1, 0);
    asm volatile("s_waitcnt vmcnt(6)" ::: "memory");
    __builtin_amdgcn_s_barrier();

#pragma unroll 1
    for (int i = 0; i < 31; ++i) {
        int k0 = 2 * i;
        PH(0, 0, ST_A(k0 + 1, 1), );
        PH(0, 2, ST_B(k0 + 2, 0), );
        PH(0, 4, ST_B(k0 + 2, 1), );
        PH(0, 6, ST_A(k0 + 2, 0), asm volatile("s_waitcnt vmcnt(6)" ::: "memory"));
        PH(1, 0, ST_A(k0 + 2, 1), );
        PH(1, 2, ST_B(k0 + 3, 0), );
        PH(1, 4, ST_B(k0 + 3, 1), );
        PH(1, 6, ST_A(k0 + 3, 0), asm volatile("s_waitcnt vmcnt(6)" ::: "memory"));
    }
    // peeled final iteration: K-tiles 62, 63 (drain)
    PH(0, 0, ST_A(63, 1), );
    PH(0, 2, , );
    PH(0, 4, , );
    PH(0, 6, , asm volatile("s_waitcnt vmcnt(0)" ::: "memory"));
    PH(1, 0, , );
    PH(1, 2, , );
    PH(1, 4, , );
    PH(1, 6, , );

    // epilogue: D layout col=lane&15, row=(lane>>4)*4+e
#pragma unroll
    for (int mi = 0; mi < 8; ++mi)
#pragma unroll
        for (int ni = 0; ni < 4; ++ni)
#pragma unroll
            for (int e = 0; e < 4; ++e) {
                int row = m0 + wm * 128 + mi * 16 + lq * 4 + e;
                int col = n0 + wn * 64 + ni * 16 + lrow;
                C[(size_t)row * NN + col] = acc[mi][ni][e];
            }
}

// ---------------------------------------------------------------------------
extern "C" void kernel_launch(void* const* d_in, const int* in_sizes, int n_in,
                              void* d_out, int out_size, void* d_ws, size_t ws_size,
                              hipStream_t stream) {
    const float* x = (const float*)d_in[0];
    const float* G = (const float*)d_in[1];
    const float* H = (const float*)d_in[2];
    float* y = (float*)d_out;

    char* ws = (char*)d_ws;
    u16* xbf = (u16*)ws;                                   // 64 MB, row-major
    u16* Wbf = (u16*)(ws + (size_t)BB * NN * 2);           // 32 MB, row-major
    float* S_T = (float*)(ws + (size_t)BB * NN * 2 + (size_t)NN * NN * 2);  // 1 MB

    hipLaunchKernelGGL(cast_x_kernel, dim3((size_t)BB * NN / 8 / 256), dim3(256), 0, stream,
                       x, xbf);
    hipLaunchKernelGGL(ksum_kernel, dim3((NN / 256) * NCHUNK), dim3(256), 0, stream, G, H, S_T);
    hipLaunchKernelGGL(kprefix_kernel, dim3(64 * 64), dim3(128), 0, stream, G, H, S_T, Wbf);
    hipLaunchKernelGGL(gemm256_kernel, dim3((BB / 256) * (NN / 256)), dim3(512), 0, stream,
                       xbf, Wbf, y);
}